// Round 1
// baseline (383.167 us; speedup 1.0000x reference)
//
#include <hip/hip_runtime.h>
#include <stdint.h>
#include <stddef.h>

// GraphSAGE-mean 2-layer pipeline on MI355X.
//   h   = relu(feat @ W_init + b_init)                      [200000,128] bf16 (ws)
//   l0: hn = segment_mean(h[src0], dst0); h1 = relu(h[:50000]@Ws + hn@Wn + b)  bf16
//   l1: hn = segment_mean(h1[src1], dst1); out = h1[:10000]@Ws + hn@Wn + b    f32
// GEMMs: mfma_f32_16x16x32_bf16 with split-precision weights (W = hi + lo bf16)
// so matmul error is ~f32-grade; only bf16 storage roundings remain.
// Scatter: padded slot array (MAXDEG=64) + wave-per-dst pull (no float atomics).

#define DIM 128
constexpr int N_SRC0 = 200000;
constexpr int N_DST0 = 50000;
constexpr int N_DST1 = 10000;
constexpr int E0 = 800000;
constexpr int E1 = 160000;
constexpr int MAXDEG = 64;   // Poisson(16): P(deg>64) ~ 1e-19; input is fixed seed

typedef __attribute__((ext_vector_type(8))) short bf16x8;   // 8 bf16 = 4 VGPRs
typedef __attribute__((ext_vector_type(4))) float f32x4;    // MFMA C/D

__device__ __forceinline__ uint16_t f2bf(float f) {
  union { float f; uint32_t u; } v; v.f = f;
  return (uint16_t)((v.u + 0x7FFFu + ((v.u >> 16) & 1u)) >> 16);  // RNE
}
__device__ __forceinline__ float bf2f(uint16_t h) {
  union { uint32_t u; float f; } v; v.u = ((uint32_t)h) << 16;
  return v.f;
}

// ---------------------------------------------------------------------------
// Pre-split W into MFMA-fragment order: Wf[plane hi/lo][kc 0..3][nt 0..7][lane][j]
// value = W[kc*32 + (lane>>4)*8 + j][nt*16 + (lane&15)]
// ---------------------------------------------------------------------------
__global__ __launch_bounds__(512) void prep_w_kernel(const float* __restrict__ W,
                                                     uint16_t* __restrict__ Wf) {
  int idx = blockIdx.x * 512 + threadIdx.x;
  if (idx >= 16384) return;
  int j = idx & 7, lane = (idx >> 3) & 63, nt = (idx >> 9) & 7, kc = idx >> 12;
  int k = kc * 32 + (lane >> 4) * 8 + j;
  int n = nt * 16 + (lane & 15);
  float v = W[k * DIM + n];
  uint16_t hi = f2bf(v);
  Wf[idx] = hi;
  Wf[16384 + idx] = f2bf(v - bf2f(hi));
}

// ---------------------------------------------------------------------------
// fc_init: h = relu(feat @ W + b), feat f32, h bf16. One wave per 16-row strip.
// A split hi/lo (features are f32) + W split hi/lo, drop lo*lo: 3 MFMAs/pair.
// ---------------------------------------------------------------------------
__global__ __launch_bounds__(256) void fc_init_kernel(
    const float* __restrict__ feat, const uint16_t* __restrict__ Wf,
    const float* __restrict__ bias, uint16_t* __restrict__ hout) {
  int wave = (blockIdx.x * 256 + threadIdx.x) >> 6;
  int nwaves = (gridDim.x * 256) >> 6;
  int lane = threadIdx.x & 63;
  int q = lane >> 4, m16 = lane & 15;

  float bv[8];
#pragma unroll
  for (int nt = 0; nt < 8; nt++) bv[nt] = bias[nt * 16 + m16];

  const int nstrips = N_SRC0 / 16;
  for (int s = wave; s < nstrips; s += nwaves) {
    int m0 = s * 16;
    f32x4 acc[8];
#pragma unroll
    for (int nt = 0; nt < 8; nt++) acc[nt] = (f32x4){0.f, 0.f, 0.f, 0.f};

#pragma unroll
    for (int kc = 0; kc < 4; kc++) {
      const float* ap = feat + (size_t)(m0 + m16) * DIM + kc * 32 + q * 8;
      float4 x0 = *(const float4*)ap;
      float4 x1 = *(const float4*)(ap + 4);
      float xs[8] = {x0.x, x0.y, x0.z, x0.w, x1.x, x1.y, x1.z, x1.w};
      bf16x8 ahi, alo;
#pragma unroll
      for (int j = 0; j < 8; j++) {
        uint16_t h = f2bf(xs[j]);
        ahi[j] = (short)h;
        alo[j] = (short)f2bf(xs[j] - bf2f(h));
      }
#pragma unroll
      for (int nt = 0; nt < 8; nt++) {
        const uint16_t* wp = Wf + (size_t)((kc * 8 + nt) * 64 + lane) * 8;
        bf16x8 wh = *(const bf16x8*)wp;
        bf16x8 wl = *(const bf16x8*)(wp + 16384);
        acc[nt] = __builtin_amdgcn_mfma_f32_16x16x32_bf16(ahi, wh, acc[nt], 0, 0, 0);
        acc[nt] = __builtin_amdgcn_mfma_f32_16x16x32_bf16(alo, wh, acc[nt], 0, 0, 0);
        acc[nt] = __builtin_amdgcn_mfma_f32_16x16x32_bf16(ahi, wl, acc[nt], 0, 0, 0);
      }
    }
#pragma unroll
    for (int nt = 0; nt < 8; nt++)
#pragma unroll
      for (int r = 0; r < 4; r++) {
        float v = fmaxf(acc[nt][r] + bv[nt], 0.f);
        hout[(size_t)(m0 + q * 4 + r) * DIM + nt * 16 + m16] = f2bf(v);
      }
  }
}

// ---------------------------------------------------------------------------
// place: slot-scatter src ids by dst. cnt[d] doubles as degree afterwards.
// ---------------------------------------------------------------------------
__global__ __launch_bounds__(256) void place_kernel(
    const int* __restrict__ src, const int* __restrict__ dst, int E,
    int* __restrict__ cnt, int* __restrict__ eslot) {
  int i = blockIdx.x * 256 + threadIdx.x;
  if (i >= E) return;
  int d = dst[i];
  int p = atomicAdd(&cnt[d], 1);
  if (p < MAXDEG) eslot[(size_t)d * MAXDEG + p] = src[i];
}

// ---------------------------------------------------------------------------
// aggregate: wave per dst, lane owns 2 feature cols; mean written as bf16.
// ---------------------------------------------------------------------------
__global__ __launch_bounds__(256) void agg_kernel(
    const int* __restrict__ eslot, const int* __restrict__ deg,
    const uint16_t* __restrict__ hsrc, uint16_t* __restrict__ hout, int n_dst) {
  int d = (blockIdx.x * 256 + threadIdx.x) >> 6;
  int lane = threadIdx.x & 63;
  if (d >= n_dst) return;
  const int* sl = eslot + (size_t)d * MAXDEG;
  int dg = deg[d];
  int dgc = dg < MAXDEG ? dg : MAXDEG;
  float a0 = 0.f, a1 = 0.f;
  int e = 0;
  for (; e + 4 <= dgc; e += 4) {
    int s0 = sl[e], s1 = sl[e + 1], s2 = sl[e + 2], s3 = sl[e + 3];
    uint32_t p0 = *(const uint32_t*)(hsrc + (size_t)s0 * DIM + lane * 2);
    uint32_t p1 = *(const uint32_t*)(hsrc + (size_t)s1 * DIM + lane * 2);
    uint32_t p2 = *(const uint32_t*)(hsrc + (size_t)s2 * DIM + lane * 2);
    uint32_t p3 = *(const uint32_t*)(hsrc + (size_t)s3 * DIM + lane * 2);
    a0 += bf2f((uint16_t)p0) + bf2f((uint16_t)p1) + bf2f((uint16_t)p2) + bf2f((uint16_t)p3);
    a1 += bf2f((uint16_t)(p0 >> 16)) + bf2f((uint16_t)(p1 >> 16)) +
          bf2f((uint16_t)(p2 >> 16)) + bf2f((uint16_t)(p3 >> 16));
  }
  for (; e < dgc; e++) {
    uint32_t p = *(const uint32_t*)(hsrc + (size_t)sl[e] * DIM + lane * 2);
    a0 += bf2f((uint16_t)p);
    a1 += bf2f((uint16_t)(p >> 16));
  }
  float inv = 1.f / fmaxf((float)dg, 1.f);
  uint32_t o = (uint32_t)f2bf(a0 * inv) | ((uint32_t)f2bf(a1 * inv) << 16);
  *(uint32_t*)(hout + (size_t)d * DIM + lane * 2) = o;
}

// ---------------------------------------------------------------------------
// sage: out = act(hself@Wself + hneigh@Wneigh + bself + bneigh)
// A operands exact bf16 -> only W split needed: 2 MFMAs per (A,W) pair.
// ---------------------------------------------------------------------------
template <bool ACT, bool OUT_BF16>
__global__ __launch_bounds__(256) void sage_kernel(
    const uint16_t* __restrict__ hself, const uint16_t* __restrict__ hneigh,
    const uint16_t* __restrict__ WfS, const uint16_t* __restrict__ WfN,
    const float* __restrict__ bS, const float* __restrict__ bN,
    void* __restrict__ outp, int n_dst) {
  int wave = (blockIdx.x * 256 + threadIdx.x) >> 6;
  int nwaves = (gridDim.x * 256) >> 6;
  int lane = threadIdx.x & 63;
  int q = lane >> 4, m16 = lane & 15;

  float bv[8];
#pragma unroll
  for (int nt = 0; nt < 8; nt++)
    bv[nt] = bS[nt * 16 + m16] + bN[nt * 16 + m16];

  const int nstrips = n_dst / 16;
  for (int s = wave; s < nstrips; s += nwaves) {
    int m0 = s * 16;
    f32x4 acc[8];
#pragma unroll
    for (int nt = 0; nt < 8; nt++) acc[nt] = (f32x4){0.f, 0.f, 0.f, 0.f};

#pragma unroll
    for (int kc = 0; kc < 4; kc++) {
      bf16x8 aS = *(const bf16x8*)(hself + (size_t)(m0 + m16) * DIM + kc * 32 + q * 8);
      bf16x8 aN = *(const bf16x8*)(hneigh + (size_t)(m0 + m16) * DIM + kc * 32 + q * 8);
#pragma unroll
      for (int nt = 0; nt < 8; nt++) {
        size_t fo = (size_t)((kc * 8 + nt) * 64 + lane) * 8;
        bf16x8 wsh = *(const bf16x8*)(WfS + fo);
        bf16x8 wsl = *(const bf16x8*)(WfS + 16384 + fo);
        bf16x8 wnh = *(const bf16x8*)(WfN + fo);
        bf16x8 wnl = *(const bf16x8*)(WfN + 16384 + fo);
        acc[nt] = __builtin_amdgcn_mfma_f32_16x16x32_bf16(aS, wsh, acc[nt], 0, 0, 0);
        acc[nt] = __builtin_amdgcn_mfma_f32_16x16x32_bf16(aS, wsl, acc[nt], 0, 0, 0);
        acc[nt] = __builtin_amdgcn_mfma_f32_16x16x32_bf16(aN, wnh, acc[nt], 0, 0, 0);
        acc[nt] = __builtin_amdgcn_mfma_f32_16x16x32_bf16(aN, wnl, acc[nt], 0, 0, 0);
      }
    }
#pragma unroll
    for (int nt = 0; nt < 8; nt++)
#pragma unroll
      for (int r = 0; r < 4; r++) {
        float v = acc[nt][r] + bv[nt];
        if (ACT) v = fmaxf(v, 0.f);
        size_t o = (size_t)(m0 + q * 4 + r) * DIM + nt * 16 + m16;
        if (OUT_BF16) ((uint16_t*)outp)[o] = f2bf(v);
        else          ((float*)outp)[o] = v;
      }
  }
}

// ---------------------------------------------------------------------------
// Workspace layout (bytes, all 256-aligned), total ~90.0 MB:
//   h     @ 0          200000*128 bf16 = 51,200,000
//   h1    @ 51,200,000  50000*128 bf16 = 12,800,000
//   hn    @ 64,000,000  50000*128 bf16 = 12,800,000
//   cnt   @ 76,800,000  50000 int      =    200,000
//   eslot @ 77,000,192  50000*64 int   = 12,800,000
//   Wf    @ 89,800,192  3 * 32768 bf16 =    196,608
// ---------------------------------------------------------------------------
extern "C" void kernel_launch(void* const* d_in, const int* in_sizes, int n_in,
                              void* d_out, int out_size, void* d_ws, size_t ws_size,
                              hipStream_t stream) {
  const float* feat   = (const float*)d_in[0];
  const int* src0     = (const int*)d_in[1];
  const int* dst0     = (const int*)d_in[2];
  const int* src1     = (const int*)d_in[3];
  const int* dst1     = (const int*)d_in[4];
  const float* W_init = (const float*)d_in[5];
  const float* b_init = (const float*)d_in[6];
  const float* W_self = (const float*)d_in[7];
  const float* b_self = (const float*)d_in[8];
  const float* W_neigh= (const float*)d_in[9];
  const float* b_neigh= (const float*)d_in[10];

  char* ws = (char*)d_ws;
  uint16_t* h    = (uint16_t*)(ws + 0);
  uint16_t* h1   = (uint16_t*)(ws + 51200000);
  uint16_t* hn   = (uint16_t*)(ws + 64000000);
  int*      cnt  = (int*)(ws + 76800000);
  int*      eslot= (int*)(ws + 77000192);
  uint16_t* WfI  = (uint16_t*)(ws + 89800192);
  uint16_t* WfS  = WfI + 32768;
  uint16_t* WfN  = WfS + 32768;

  // weight prep (frag-order hi/lo split)
  prep_w_kernel<<<32, 512, 0, stream>>>(W_init, WfI);
  prep_w_kernel<<<32, 512, 0, stream>>>(W_self, WfS);
  prep_w_kernel<<<32, 512, 0, stream>>>(W_neigh, WfN);

  // h = relu(feat @ W_init + b_init)
  fc_init_kernel<<<512, 256, 0, stream>>>(feat, WfI, b_init, h);

  // ---- layer 0 ----
  hipMemsetAsync(cnt, 0, N_DST0 * sizeof(int), stream);
  place_kernel<<<(E0 + 255) / 256, 256, 0, stream>>>(src0, dst0, E0, cnt, eslot);
  agg_kernel<<<N_DST0 / 4, 256, 0, stream>>>(eslot, cnt, h, hn, N_DST0);
  sage_kernel<true, true><<<256, 256, 0, stream>>>(h, hn, WfS, WfN, b_self, b_neigh,
                                                   h1, N_DST0);

  // ---- layer 1 ----
  hipMemsetAsync(cnt, 0, N_DST1 * sizeof(int), stream);
  place_kernel<<<(E1 + 255) / 256, 256, 0, stream>>>(src1, dst1, E1, cnt, eslot);
  agg_kernel<<<N_DST1 / 4, 256, 0, stream>>>(eslot, cnt, h1, hn, N_DST1);
  sage_kernel<false, false><<<256, 256, 0, stream>>>(h1, hn, WfS, WfN, b_self, b_neigh,
                                                     d_out, N_DST1);
}

// Round 2
// 326.514 us; speedup vs baseline: 1.1735x; 1.1735x over previous
//
#include <hip/hip_runtime.h>
#include <stdint.h>
#include <stddef.h>

// GraphSAGE-mean 2-layer pipeline on MI355X — round 2.
//   h   = relu(feat @ W_init + b_init)                      [200000,128] bf16 (ws)
//   l0: hn = segment_mean(h[src0], dst0); h1 = relu(h[:50000]@Ws + hn@Wn + b)  bf16
//   l1: hn = segment_mean(h1[src1], dst1); out = h1[:10000]@Ws + hn@Wn + b    f32
//
// R2 changes vs R1 (which was latency-bound: sage Occ 0.085%, fc_init Occ 9.5%):
//  - single-plane bf16 W (lo-planes dropped: absmax was storage-rounding-bound
//    at 3.9e-3 vs 15e-3 threshold; halves MFMA + W traffic)
//  - W fragments staged in LDS (fc: 32 KB; sage: Ws+Wn = 64 KB exactly) so the
//    MFMA dependence chain reads LDS (~12 cyc) instead of L2/HBM (~200-900 cyc)
//  - bigger grids (fc 1024 blk, sage0 512 blk = 2 blk/CU LDS limit)
//  - prep fused to one kernel; one memset covers cnt0+cnt1; eslot reused
//    sequentially between layers (workspace stays within R1's ~90 MB footprint)

#define DIM 128
constexpr int N_SRC0 = 200000;
constexpr int N_DST0 = 50000;
constexpr int N_DST1 = 10000;
constexpr int E0 = 800000;
constexpr int E1 = 160000;
constexpr int MAXDEG = 64;   // Poisson(16): max observed deg ~40 over 50k bins

typedef __attribute__((ext_vector_type(8))) short bf16x8;   // 8 bf16 = 4 VGPRs
typedef __attribute__((ext_vector_type(4))) float f32x4;    // MFMA C/D

__device__ __forceinline__ uint16_t f2bf(float f) {
  union { float f; uint32_t u; } v; v.f = f;
  return (uint16_t)((v.u + 0x7FFFu + ((v.u >> 16) & 1u)) >> 16);  // RNE
}
__device__ __forceinline__ float bf2f(uint16_t h) {
  union { uint32_t u; float f; } v; v.u = ((uint32_t)h) << 16;
  return v.f;
}

// ---------------------------------------------------------------------------
// prep: reformat 3 weight matrices (f32) into MFMA-fragment-order bf16 planes.
// Wf[m][((kc*8+nt)*64+lane)*8+j] = bf16(W_m[kc*32+(lane>>4)*8+j][nt*16+(lane&15)])
// ---------------------------------------------------------------------------
__global__ __launch_bounds__(512) void prep_w_kernel(
    const float* __restrict__ W0, const float* __restrict__ W1,
    const float* __restrict__ W2, uint16_t* __restrict__ Wf) {
  int gid = blockIdx.x * 512 + threadIdx.x;
  if (gid >= 3 * 16384) return;
  int m = gid >> 14, idx = gid & 16383;
  const float* W = m == 0 ? W0 : (m == 1 ? W1 : W2);
  int j = idx & 7, lane = (idx >> 3) & 63, nt = (idx >> 9) & 7, kc = idx >> 12;
  int k = kc * 32 + (lane >> 4) * 8 + j;
  int n = nt * 16 + (lane & 15);
  Wf[gid] = f2bf(W[k * DIM + n]);
}

// ---------------------------------------------------------------------------
// fc_init: h = relu(feat @ W + b), feat f32, h bf16. Wave per 16-row strip,
// W staged in LDS (32 KB), grid-stride over strips.
// ---------------------------------------------------------------------------
__global__ __launch_bounds__(256) void fc_init_kernel(
    const float* __restrict__ feat, const uint16_t* __restrict__ Wf,
    const float* __restrict__ bias, uint16_t* __restrict__ hout) {
  __shared__ uint16_t wl[16384];                        // 32 KB
  {
    const uint4* g = (const uint4*)Wf;
    uint4* s = (uint4*)wl;
    for (int i = threadIdx.x; i < 2048; i += 256) s[i] = g[i];
  }
  __syncthreads();

  int wave = (blockIdx.x * 256 + threadIdx.x) >> 6;
  int nwaves = (gridDim.x * 256) >> 6;
  int lane = threadIdx.x & 63;
  int q = lane >> 4, m16 = lane & 15;

  float bv[8];
#pragma unroll
  for (int nt = 0; nt < 8; nt++) bv[nt] = bias[nt * 16 + m16];

  const int nstrips = N_SRC0 / 16;
  for (int s = wave; s < nstrips; s += nwaves) {
    int m0 = s * 16;
    f32x4 acc[8];
#pragma unroll
    for (int nt = 0; nt < 8; nt++) acc[nt] = (f32x4){0.f, 0.f, 0.f, 0.f};

#pragma unroll
    for (int kc = 0; kc < 4; kc++) {
      const float* ap = feat + (size_t)(m0 + m16) * DIM + kc * 32 + q * 8;
      float4 x0 = *(const float4*)ap;
      float4 x1 = *(const float4*)(ap + 4);
      float xs[8] = {x0.x, x0.y, x0.z, x0.w, x1.x, x1.y, x1.z, x1.w};
      bf16x8 a;
#pragma unroll
      for (int j = 0; j < 8; j++) a[j] = (short)f2bf(xs[j]);
#pragma unroll
      for (int nt = 0; nt < 8; nt++) {
        bf16x8 w = *(const bf16x8*)&wl[(size_t)((kc * 8 + nt) * 64 + lane) * 8];
        acc[nt] = __builtin_amdgcn_mfma_f32_16x16x32_bf16(a, w, acc[nt], 0, 0, 0);
      }
    }
#pragma unroll
    for (int nt = 0; nt < 8; nt++)
#pragma unroll
      for (int r = 0; r < 4; r++) {
        float v = fmaxf(acc[nt][r] + bv[nt], 0.f);
        hout[(size_t)(m0 + q * 4 + r) * DIM + nt * 16 + m16] = f2bf(v);
      }
  }
}

// ---------------------------------------------------------------------------
// place: slot-scatter src ids by dst. cnt[d] doubles as degree afterwards.
// ---------------------------------------------------------------------------
__global__ __launch_bounds__(256) void place_kernel(
    const int* __restrict__ src, const int* __restrict__ dst, int E,
    int* __restrict__ cnt, int* __restrict__ eslot) {
  int i = blockIdx.x * 256 + threadIdx.x;
  if (i >= E) return;
  int d = dst[i];
  int p = atomicAdd(&cnt[d], 1);
  if (p < MAXDEG) eslot[(size_t)d * MAXDEG + p] = src[i];
}

// ---------------------------------------------------------------------------
// aggregate: wave per dst, lane owns 2 feature cols; mean written as bf16.
// ---------------------------------------------------------------------------
__global__ __launch_bounds__(256) void agg_kernel(
    const int* __restrict__ eslot, const int* __restrict__ deg,
    const uint16_t* __restrict__ hsrc, uint16_t* __restrict__ hout, int n_dst) {
  int d = (blockIdx.x * 256 + threadIdx.x) >> 6;
  int lane = threadIdx.x & 63;
  if (d >= n_dst) return;
  const int* sl = eslot + (size_t)d * MAXDEG;
  int dg = deg[d];
  int dgc = dg < MAXDEG ? dg : MAXDEG;
  float a0 = 0.f, a1 = 0.f;
  int e = 0;
  for (; e + 4 <= dgc; e += 4) {
    int s0 = sl[e], s1 = sl[e + 1], s2 = sl[e + 2], s3 = sl[e + 3];
    uint32_t p0 = *(const uint32_t*)(hsrc + (size_t)s0 * DIM + lane * 2);
    uint32_t p1 = *(const uint32_t*)(hsrc + (size_t)s1 * DIM + lane * 2);
    uint32_t p2 = *(const uint32_t*)(hsrc + (size_t)s2 * DIM + lane * 2);
    uint32_t p3 = *(const uint32_t*)(hsrc + (size_t)s3 * DIM + lane * 2);
    a0 += bf2f((uint16_t)p0) + bf2f((uint16_t)p1) + bf2f((uint16_t)p2) + bf2f((uint16_t)p3);
    a1 += bf2f((uint16_t)(p0 >> 16)) + bf2f((uint16_t)(p1 >> 16)) +
          bf2f((uint16_t)(p2 >> 16)) + bf2f((uint16_t)(p3 >> 16));
  }
  for (; e < dgc; e++) {
    uint32_t p = *(const uint32_t*)(hsrc + (size_t)sl[e] * DIM + lane * 2);
    a0 += bf2f((uint16_t)p);
    a1 += bf2f((uint16_t)(p >> 16));
  }
  float inv = 1.f / fmaxf((float)dg, 1.f);
  uint32_t o = (uint32_t)f2bf(a0 * inv) | ((uint32_t)f2bf(a1 * inv) << 16);
  *(uint32_t*)(hout + (size_t)d * DIM + lane * 2) = o;
}

// ---------------------------------------------------------------------------
// sage: out = act(hself@Wself + hneigh@Wneigh + bself + bneigh)
// Both W planes staged in LDS (64 KB exactly -> 2 blocks/CU).
// ---------------------------------------------------------------------------
template <bool ACT, bool OUT_BF16>
__global__ __launch_bounds__(256) void sage_kernel(
    const uint16_t* __restrict__ hself, const uint16_t* __restrict__ hneigh,
    const uint16_t* __restrict__ WfS, const uint16_t* __restrict__ WfN,
    const float* __restrict__ bS, const float* __restrict__ bN,
    void* __restrict__ outp, int n_dst) {
  __shared__ uint16_t wS[16384];                        // 32 KB
  __shared__ uint16_t wN[16384];                        // 32 KB
  {
    const uint4* gS = (const uint4*)WfS;
    const uint4* gN = (const uint4*)WfN;
    uint4* sS = (uint4*)wS;
    uint4* sN = (uint4*)wN;
    for (int i = threadIdx.x; i < 2048; i += 256) { sS[i] = gS[i]; sN[i] = gN[i]; }
  }
  __syncthreads();

  int wave = (blockIdx.x * 256 + threadIdx.x) >> 6;
  int nwaves = (gridDim.x * 256) >> 6;
  int lane = threadIdx.x & 63;
  int q = lane >> 4, m16 = lane & 15;

  float bv[8];
#pragma unroll
  for (int nt = 0; nt < 8; nt++)
    bv[nt] = bS[nt * 16 + m16] + bN[nt * 16 + m16];

  const int nstrips = n_dst / 16;
  for (int s = wave; s < nstrips; s += nwaves) {
    int m0 = s * 16;
    f32x4 acc[8];
#pragma unroll
    for (int nt = 0; nt < 8; nt++) acc[nt] = (f32x4){0.f, 0.f, 0.f, 0.f};

#pragma unroll
    for (int kc = 0; kc < 4; kc++) {
      bf16x8 aS = *(const bf16x8*)(hself + (size_t)(m0 + m16) * DIM + kc * 32 + q * 8);
      bf16x8 aN = *(const bf16x8*)(hneigh + (size_t)(m0 + m16) * DIM + kc * 32 + q * 8);
#pragma unroll
      for (int nt = 0; nt < 8; nt++) {
        size_t fo = (size_t)((kc * 8 + nt) * 64 + lane) * 8;
        bf16x8 ws = *(const bf16x8*)&wS[fo];
        bf16x8 wn = *(const bf16x8*)&wN[fo];
        acc[nt] = __builtin_amdgcn_mfma_f32_16x16x32_bf16(aS, ws, acc[nt], 0, 0, 0);
        acc[nt] = __builtin_amdgcn_mfma_f32_16x16x32_bf16(aN, wn, acc[nt], 0, 0, 0);
      }
    }
#pragma unroll
    for (int nt = 0; nt < 8; nt++)
#pragma unroll
      for (int r = 0; r < 4; r++) {
        float v = acc[nt][r] + bv[nt];
        if (ACT) v = fmaxf(v, 0.f);
        size_t o = (size_t)(m0 + q * 4 + r) * DIM + nt * 16 + m16;
        if (OUT_BF16) ((uint16_t*)outp)[o] = f2bf(v);
        else          ((float*)outp)[o] = v;
      }
  }
}

// ---------------------------------------------------------------------------
// Workspace layout (bytes), total 89,938,304 (< R1's working 89,996,800):
//   h     @ 0           200000*128 bf16 = 51,200,000
//   h1    @ 51,200,000   50000*128 bf16 = 12,800,000
//   hn    @ 64,000,000   50000*128 bf16 = 12,800,000
//   cnt0  @ 76,800,000   50000 int      =    200,000
//   cnt1  @ 77,000,000   10000 int      =     40,000   (one memset covers both)
//   eslot @ 77,040,000   50000*64 int   = 12,800,000   (reused by layer 1)
//   Wf    @ 89,840,000   3*16384 bf16   =     98,304
// ---------------------------------------------------------------------------
extern "C" void kernel_launch(void* const* d_in, const int* in_sizes, int n_in,
                              void* d_out, int out_size, void* d_ws, size_t ws_size,
                              hipStream_t stream) {
  const float* feat   = (const float*)d_in[0];
  const int* src0     = (const int*)d_in[1];
  const int* dst0     = (const int*)d_in[2];
  const int* src1     = (const int*)d_in[3];
  const int* dst1     = (const int*)d_in[4];
  const float* W_init = (const float*)d_in[5];
  const float* b_init = (const float*)d_in[6];
  const float* W_self = (const float*)d_in[7];
  const float* b_self = (const float*)d_in[8];
  const float* W_neigh= (const float*)d_in[9];
  const float* b_neigh= (const float*)d_in[10];

  char* ws = (char*)d_ws;
  uint16_t* h    = (uint16_t*)(ws + 0);
  uint16_t* h1   = (uint16_t*)(ws + 51200000);
  uint16_t* hn   = (uint16_t*)(ws + 64000000);
  int*      cnt0 = (int*)(ws + 76800000);
  int*      cnt1 = (int*)(ws + 77000000);
  int*      eslot= (int*)(ws + 77040000);
  uint16_t* WfI  = (uint16_t*)(ws + 89840000);
  uint16_t* WfS  = WfI + 16384;
  uint16_t* WfN  = WfS + 16384;

  hipMemsetAsync(cnt0, 0, 240000, stream);  // cnt0 + cnt1 contiguous
  prep_w_kernel<<<96, 512, 0, stream>>>(W_init, W_self, W_neigh, WfI);
  place_kernel<<<(E0 + 255) / 256, 256, 0, stream>>>(src0, dst0, E0, cnt0, eslot);

  // h = relu(feat @ W_init + b_init)
  fc_init_kernel<<<1024, 256, 0, stream>>>(feat, WfI, b_init, h);

  // ---- layer 0 ----
  agg_kernel<<<N_DST0 / 4, 256, 0, stream>>>(eslot, cnt0, h, hn, N_DST0);
  sage_kernel<true, true><<<512, 256, 0, stream>>>(h, hn, WfS, WfN, b_self, b_neigh,
                                                   h1, N_DST0);

  // ---- layer 1 ---- (eslot reused; place1 serializes after agg0 on stream)
  place_kernel<<<(E1 + 255) / 256, 256, 0, stream>>>(src1, dst1, E1, cnt1, eslot);
  agg_kernel<<<N_DST1 / 4, 256, 0, stream>>>(eslot, cnt1, h1, hn, N_DST1);
  sage_kernel<false, false><<<160, 256, 0, stream>>>(h1, hn, WfS, WfN, b_self, b_neigh,
                                                     d_out, N_DST1);
}

// Round 3
// 313.509 us; speedup vs baseline: 1.2222x; 1.0415x over previous
//
#include <hip/hip_runtime.h>
#include <stdint.h>
#include <stddef.h>

// GraphSAGE-mean 2-layer pipeline on MI355X — round 3.
//   h   = relu(feat @ W_init + b_init)                      [200000,128] bf16 (ws)
//   l0: hn = segment_mean(h[src0], dst0); h1 = relu(h[:50000]@Ws + hn@Wn + b)  bf16
//   l1: hn = segment_mean(h1[src1], dst1); out = h1[:10000]@Ws + hn@Wn + b    f32
//
// R3 changes vs R2 (fc_init was load-latency serialized: 2923 cyc/strip ~= 4x
// HBM latency; measured 6.75 B/cyc/CU read BW vs ~43 possible):
//  - fc_init/sage: explicit 8-load burst per strip + next-strip register
//    prefetch -> one latency exposure per strip, overlapped with MFMA
//  - prep kernel also zeroes cnt0/cnt1 (memset node dropped)
//  - place0+place1 fused into one kernel (separate eslot1; ws_size ~409.6 MB
//    per the harness poison fill, we use 92.5 MB)
//  - 7 graph nodes: prep -> place -> fc_init -> agg0 -> sage0 -> agg1 -> sage1

#define DIM 128
constexpr int N_SRC0 = 200000;
constexpr int N_DST0 = 50000;
constexpr int N_DST1 = 10000;
constexpr int E0 = 800000;
constexpr int E1 = 160000;
constexpr int MAXDEG = 64;   // Poisson(16): P(deg>64) negligible, input fixed seed

typedef __attribute__((ext_vector_type(8))) short bf16x8;   // 8 bf16 = 4 VGPRs
typedef __attribute__((ext_vector_type(4))) float f32x4;    // MFMA C/D

__device__ __forceinline__ uint16_t f2bf(float f) {
  union { float f; uint32_t u; } v; v.f = f;
  return (uint16_t)((v.u + 0x7FFFu + ((v.u >> 16) & 1u)) >> 16);  // RNE
}
__device__ __forceinline__ float bf2f(uint16_t h) {
  union { uint32_t u; float f; } v; v.u = ((uint32_t)h) << 16;
  return v.f;
}

// ---------------------------------------------------------------------------
// prep: reformat 3 weight matrices (f32) into MFMA-fragment-order bf16 planes,
// and zero the degree counters (replaces the memset node).
// Wf[m][((kc*8+nt)*64+lane)*8+j] = bf16(W_m[kc*32+(lane>>4)*8+j][nt*16+(lane&15)])
// ---------------------------------------------------------------------------
__global__ __launch_bounds__(512) void prep_w_kernel(
    const float* __restrict__ W0, const float* __restrict__ W1,
    const float* __restrict__ W2, uint16_t* __restrict__ Wf,
    int* __restrict__ cnt, int ncnt) {
  int gid = blockIdx.x * 512 + threadIdx.x;
  if (gid < 3 * 16384) {
    int m = gid >> 14, idx = gid & 16383;
    const float* W = m == 0 ? W0 : (m == 1 ? W1 : W2);
    int j = idx & 7, lane = (idx >> 3) & 63, nt = (idx >> 9) & 7, kc = idx >> 12;
    int k = kc * 32 + (lane >> 4) * 8 + j;
    int n = nt * 16 + (lane & 15);
    Wf[gid] = f2bf(W[k * DIM + n]);
  }
  int z = gid - 3 * 16384;
  if (z >= 0 && z < ncnt) cnt[z] = 0;
}

// ---------------------------------------------------------------------------
// place: slot-scatter src ids by dst, both layers in one dispatch.
// cnt[d] doubles as degree afterwards.
// ---------------------------------------------------------------------------
__global__ __launch_bounds__(256) void place_kernel(
    const int* __restrict__ src0, const int* __restrict__ dst0,
    const int* __restrict__ src1, const int* __restrict__ dst1,
    int* __restrict__ cnt0, int* __restrict__ cnt1,
    int* __restrict__ eslot0, int* __restrict__ eslot1) {
  int i = blockIdx.x * 256 + threadIdx.x;
  if (i < E0) {
    int d = dst0[i];
    int p = atomicAdd(&cnt0[d], 1);
    if (p < MAXDEG) eslot0[(size_t)d * MAXDEG + p] = src0[i];
  } else if (i - E0 < E1) {
    int j = i - E0;
    int d = dst1[j];
    int p = atomicAdd(&cnt1[d], 1);
    if (p < MAXDEG) eslot1[(size_t)d * MAXDEG + p] = src1[j];
  }
}

// ---------------------------------------------------------------------------
// fc_init: h = relu(feat @ W + b), feat f32, h bf16. Wave per 16-row strip,
// W in LDS. All 8 A-loads issued as one burst; next strip prefetched into
// registers while current strip computes (kills the 4x-latency serialization).
// ---------------------------------------------------------------------------
__global__ __launch_bounds__(256) void fc_init_kernel(
    const float* __restrict__ feat, const uint16_t* __restrict__ Wf,
    const float* __restrict__ bias, uint16_t* __restrict__ hout) {
  __shared__ uint16_t wl[16384];                        // 32 KB
  {
    const uint4* g = (const uint4*)Wf;
    uint4* s = (uint4*)wl;
    for (int i = threadIdx.x; i < 2048; i += 256) s[i] = g[i];
  }
  __syncthreads();

  int wave = (blockIdx.x * 256 + threadIdx.x) >> 6;
  int nwaves = (gridDim.x * 256) >> 6;
  int lane = threadIdx.x & 63;
  int q = lane >> 4, m16 = lane & 15;

  float bv[8];
#pragma unroll
  for (int nt = 0; nt < 8; nt++) bv[nt] = bias[nt * 16 + m16];

  const int nstrips = N_SRC0 / 16;
  int s = wave;
  float4 X[8];
  if (s < nstrips) {
    const float* ap = feat + (size_t)(s * 16 + m16) * DIM + q * 8;
#pragma unroll
    for (int kc = 0; kc < 4; kc++) {
      X[2 * kc]     = *(const float4*)(ap + kc * 32);
      X[2 * kc + 1] = *(const float4*)(ap + kc * 32 + 4);
    }
  }

  while (s < nstrips) {
    int sn = s + nwaves;
    float4 Y[8];
    if (sn < nstrips) {
      const float* ap = feat + (size_t)(sn * 16 + m16) * DIM + q * 8;
#pragma unroll
      for (int kc = 0; kc < 4; kc++) {
        Y[2 * kc]     = *(const float4*)(ap + kc * 32);
        Y[2 * kc + 1] = *(const float4*)(ap + kc * 32 + 4);
      }
    }

    f32x4 acc[8];
#pragma unroll
    for (int nt = 0; nt < 8; nt++) acc[nt] = (f32x4){0.f, 0.f, 0.f, 0.f};

#pragma unroll
    for (int kc = 0; kc < 4; kc++) {
      float xs[8] = {X[2 * kc].x, X[2 * kc].y, X[2 * kc].z, X[2 * kc].w,
                     X[2 * kc + 1].x, X[2 * kc + 1].y, X[2 * kc + 1].z, X[2 * kc + 1].w};
      bf16x8 a;
#pragma unroll
      for (int j = 0; j < 8; j++) a[j] = (short)f2bf(xs[j]);
#pragma unroll
      for (int nt = 0; nt < 8; nt++) {
        bf16x8 w = *(const bf16x8*)&wl[(size_t)((kc * 8 + nt) * 64 + lane) * 8];
        acc[nt] = __builtin_amdgcn_mfma_f32_16x16x32_bf16(a, w, acc[nt], 0, 0, 0);
      }
    }

    int m0 = s * 16;
#pragma unroll
    for (int nt = 0; nt < 8; nt++)
#pragma unroll
      for (int r = 0; r < 4; r++) {
        float v = fmaxf(acc[nt][r] + bv[nt], 0.f);
        hout[(size_t)(m0 + q * 4 + r) * DIM + nt * 16 + m16] = f2bf(v);
      }

#pragma unroll
    for (int i = 0; i < 8; i++) X[i] = Y[i];
    s = sn;
  }
}

// ---------------------------------------------------------------------------
// aggregate: wave per dst, lane owns 2 feature cols; mean written as bf16.
// ---------------------------------------------------------------------------
__global__ __launch_bounds__(256) void agg_kernel(
    const int* __restrict__ eslot, const int* __restrict__ deg,
    const uint16_t* __restrict__ hsrc, uint16_t* __restrict__ hout, int n_dst) {
  int d = (blockIdx.x * 256 + threadIdx.x) >> 6;
  int lane = threadIdx.x & 63;
  if (d >= n_dst) return;
  const int* sl = eslot + (size_t)d * MAXDEG;
  int dg = deg[d];
  int dgc = dg < MAXDEG ? dg : MAXDEG;
  float a0 = 0.f, a1 = 0.f;
  int e = 0;
  for (; e + 4 <= dgc; e += 4) {
    int s0 = sl[e], s1 = sl[e + 1], s2 = sl[e + 2], s3 = sl[e + 3];
    uint32_t p0 = *(const uint32_t*)(hsrc + (size_t)s0 * DIM + lane * 2);
    uint32_t p1 = *(const uint32_t*)(hsrc + (size_t)s1 * DIM + lane * 2);
    uint32_t p2 = *(const uint32_t*)(hsrc + (size_t)s2 * DIM + lane * 2);
    uint32_t p3 = *(const uint32_t*)(hsrc + (size_t)s3 * DIM + lane * 2);
    a0 += bf2f((uint16_t)p0) + bf2f((uint16_t)p1) + bf2f((uint16_t)p2) + bf2f((uint16_t)p3);
    a1 += bf2f((uint16_t)(p0 >> 16)) + bf2f((uint16_t)(p1 >> 16)) +
          bf2f((uint16_t)(p2 >> 16)) + bf2f((uint16_t)(p3 >> 16));
  }
  for (; e < dgc; e++) {
    uint32_t p = *(const uint32_t*)(hsrc + (size_t)sl[e] * DIM + lane * 2);
    a0 += bf2f((uint16_t)p);
    a1 += bf2f((uint16_t)(p >> 16));
  }
  float inv = 1.f / fmaxf((float)dg, 1.f);
  uint32_t o = (uint32_t)f2bf(a0 * inv) | ((uint32_t)f2bf(a1 * inv) << 16);
  *(uint32_t*)(hout + (size_t)d * DIM + lane * 2) = o;
}

// ---------------------------------------------------------------------------
// sage: out = act(hself@Wself + hneigh@Wneigh + bself + bneigh)
// Both W planes in LDS (64 KB). Burst A-loads + next-strip register prefetch.
// ---------------------------------------------------------------------------
template <bool ACT, bool OUT_BF16>
__global__ __launch_bounds__(256) void sage_kernel(
    const uint16_t* __restrict__ hself, const uint16_t* __restrict__ hneigh,
    const uint16_t* __restrict__ WfS, const uint16_t* __restrict__ WfN,
    const float* __restrict__ bS, const float* __restrict__ bN,
    void* __restrict__ outp, int n_dst) {
  __shared__ uint16_t wS[16384];                        // 32 KB
  __shared__ uint16_t wN[16384];                        // 32 KB
  {
    const uint4* gS = (const uint4*)WfS;
    const uint4* gN = (const uint4*)WfN;
    uint4* sS = (uint4*)wS;
    uint4* sN = (uint4*)wN;
    for (int i = threadIdx.x; i < 2048; i += 256) { sS[i] = gS[i]; sN[i] = gN[i]; }
  }
  __syncthreads();

  int wave = (blockIdx.x * 256 + threadIdx.x) >> 6;
  int nwaves = (gridDim.x * 256) >> 6;
  int lane = threadIdx.x & 63;
  int q = lane >> 4, m16 = lane & 15;

  float bv[8];
#pragma unroll
  for (int nt = 0; nt < 8; nt++)
    bv[nt] = bS[nt * 16 + m16] + bN[nt * 16 + m16];

  const int nstrips = n_dst / 16;
  int s = wave;
  bf16x8 XS[4], XN[4];
  if (s < nstrips) {
    size_t ro = (size_t)(s * 16 + m16) * DIM + q * 8;
#pragma unroll
    for (int kc = 0; kc < 4; kc++) {
      XS[kc] = *(const bf16x8*)(hself + ro + kc * 32);
      XN[kc] = *(const bf16x8*)(hneigh + ro + kc * 32);
    }
  }

  while (s < nstrips) {
    int sn = s + nwaves;
    bf16x8 YS[4], YN[4];
    if (sn < nstrips) {
      size_t ro = (size_t)(sn * 16 + m16) * DIM + q * 8;
#pragma unroll
      for (int kc = 0; kc < 4; kc++) {
        YS[kc] = *(const bf16x8*)(hself + ro + kc * 32);
        YN[kc] = *(const bf16x8*)(hneigh + ro + kc * 32);
      }
    }

    f32x4 acc[8];
#pragma unroll
    for (int nt = 0; nt < 8; nt++) acc[nt] = (f32x4){0.f, 0.f, 0.f, 0.f};

#pragma unroll
    for (int kc = 0; kc < 4; kc++) {
#pragma unroll
      for (int nt = 0; nt < 8; nt++) {
        size_t fo = (size_t)((kc * 8 + nt) * 64 + lane) * 8;
        bf16x8 ws = *(const bf16x8*)&wS[fo];
        bf16x8 wn = *(const bf16x8*)&wN[fo];
        acc[nt] = __builtin_amdgcn_mfma_f32_16x16x32_bf16(XS[kc], ws, acc[nt], 0, 0, 0);
        acc[nt] = __builtin_amdgcn_mfma_f32_16x16x32_bf16(XN[kc], wn, acc[nt], 0, 0, 0);
      }
    }

    int m0 = s * 16;
#pragma unroll
    for (int nt = 0; nt < 8; nt++)
#pragma unroll
      for (int r = 0; r < 4; r++) {
        float v = acc[nt][r] + bv[nt];
        if (ACT) v = fmaxf(v, 0.f);
        size_t o = (size_t)(m0 + q * 4 + r) * DIM + nt * 16 + m16;
        if (OUT_BF16) ((uint16_t*)outp)[o] = f2bf(v);
        else          ((float*)outp)[o] = v;
      }

#pragma unroll
    for (int i = 0; i < 4; i++) { XS[i] = YS[i]; XN[i] = YN[i]; }
    s = sn;
  }
}

// ---------------------------------------------------------------------------
// Workspace layout (bytes), total 92,498,304 (ws_size ~409.6 MB per harness fill):
//   h      @ 0           200000*128 bf16 = 51,200,000
//   h1     @ 51,200,000   50000*128 bf16 = 12,800,000
//   hn     @ 64,000,000   50000*128 bf16 = 12,800,000
//   cnt0   @ 76,800,000   50000 int      =    200,000
//   cnt1   @ 77,000,000   10000 int      =     40,000
//   eslot0 @ 77,040,000   50000*64 int   = 12,800,000
//   eslot1 @ 89,840,000   10000*64 int   =  2,560,000
//   Wf     @ 92,400,000   3*16384 bf16   =     98,304
// ---------------------------------------------------------------------------
extern "C" void kernel_launch(void* const* d_in, const int* in_sizes, int n_in,
                              void* d_out, int out_size, void* d_ws, size_t ws_size,
                              hipStream_t stream) {
  const float* feat   = (const float*)d_in[0];
  const int* src0     = (const int*)d_in[1];
  const int* dst0     = (const int*)d_in[2];
  const int* src1     = (const int*)d_in[3];
  const int* dst1     = (const int*)d_in[4];
  const float* W_init = (const float*)d_in[5];
  const float* b_init = (const float*)d_in[6];
  const float* W_self = (const float*)d_in[7];
  const float* b_self = (const float*)d_in[8];
  const float* W_neigh= (const float*)d_in[9];
  const float* b_neigh= (const float*)d_in[10];

  char* ws = (char*)d_ws;
  uint16_t* h     = (uint16_t*)(ws + 0);
  uint16_t* h1    = (uint16_t*)(ws + 51200000);
  uint16_t* hn    = (uint16_t*)(ws + 64000000);
  int*      cnt0  = (int*)(ws + 76800000);
  int*      cnt1  = (int*)(ws + 77000000);
  int*      eslot0= (int*)(ws + 77040000);
  int*      eslot1= (int*)(ws + 89840000);
  uint16_t* WfI   = (uint16_t*)(ws + 92400000);
  uint16_t* WfS   = WfI + 16384;
  uint16_t* WfN   = WfS + 16384;

  // prep W fragments + zero cnt0/cnt1 (contiguous 60000 ints)
  prep_w_kernel<<<214, 512, 0, stream>>>(W_init, W_self, W_neigh, WfI, cnt0, 60000);
  // both layers' edge scatter in one dispatch
  place_kernel<<<(E0 + E1 + 255) / 256, 256, 0, stream>>>(
      src0, dst0, src1, dst1, cnt0, cnt1, eslot0, eslot1);

  // h = relu(feat @ W_init + b_init)
  fc_init_kernel<<<768, 256, 0, stream>>>(feat, WfI, b_init, h);

  // ---- layer 0 ----
  agg_kernel<<<N_DST0 / 4, 256, 0, stream>>>(eslot0, cnt0, h, hn, N_DST0);
  sage_kernel<true, true><<<512, 256, 0, stream>>>(h, hn, WfS, WfN, b_self, b_neigh,
                                                   h1, N_DST0);

  // ---- layer 1 ----
  agg_kernel<<<N_DST1 / 4, 256, 0, stream>>>(eslot1, cnt1, h1, hn, N_DST1);
  sage_kernel<false, false><<<160, 256, 0, stream>>>(h1, hn, WfS, WfN, b_self, b_neigh,
                                                     d_out, N_DST1);
}

// Round 4
// 306.115 us; speedup vs baseline: 1.2517x; 1.0242x over previous
//
#include <hip/hip_runtime.h>
#include <stdint.h>
#include <stddef.h>

// GraphSAGE-mean 2-layer pipeline on MI355X — round 4.
//   h   = relu(feat @ W_init + b_init)                      [200000,128] bf16 (ws)
//   l0: hn = segment_mean(h[src0], dst0); h1 = relu(h[:50000]@Ws + hn@Wn + b)  bf16
//   l1: hn = segment_mean(h1[src1], dst1); out = h1[:10000]@Ws + hn@Wn + b    f32
//
// R4 changes vs R3:
//  - place: WRITE_SIZE was 56.5 MB for 3.84 MB payload (64B-line amplification
//    from cross-XCD scattered 4B writes). Now dst-partitioned: partition =
//    blockIdx&7 (XCD round-robin heuristic); each partition re-reads all edges
//    (L3-absorbed) but writes only its 1.6 MB slot slice -> L2-resident, lines
//    fill before eviction.
//  - fc_init: R3 wave-level prefetch was a no-op (59.7 -> 59.7; 8 loads/wave is
//    too little MLP). Now m97-style: 32-row feat tiles double-buffered via
//    global_load_lds width=16 (block-cooperative staging, ~32 KB/CU in flight),
//    W resident in LDS. 64 KB LDS -> 2 blocks/CU.

#define DIM 128
constexpr int N_SRC0 = 200000;
constexpr int N_DST0 = 50000;
constexpr int N_DST1 = 10000;
constexpr int E0 = 800000;
constexpr int E1 = 160000;
constexpr int MAXDEG = 64;   // Poisson(16): P(deg>64) ~ e^-42 * 50k — impossible

typedef __attribute__((ext_vector_type(8))) short bf16x8;   // 8 bf16 = 4 VGPRs
typedef __attribute__((ext_vector_type(4))) float f32x4;    // MFMA C/D

__device__ __forceinline__ uint16_t f2bf(float f) {
  union { float f; uint32_t u; } v; v.f = f;
  return (uint16_t)((v.u + 0x7FFFu + ((v.u >> 16) & 1u)) >> 16);  // RNE
}
__device__ __forceinline__ float bf2f(uint16_t h) {
  union { uint32_t u; float f; } v; v.u = ((uint32_t)h) << 16;
  return v.f;
}

// ---------------------------------------------------------------------------
// prep: reformat 3 weight matrices (f32) into MFMA-fragment-order bf16 planes,
// and zero the degree counters.
// Wf[m][((kc*8+nt)*64+lane)*8+j] = bf16(W_m[kc*32+(lane>>4)*8+j][nt*16+(lane&15)])
// ---------------------------------------------------------------------------
__global__ __launch_bounds__(512) void prep_w_kernel(
    const float* __restrict__ W0, const float* __restrict__ W1,
    const float* __restrict__ W2, uint16_t* __restrict__ Wf,
    int* __restrict__ cnt, int ncnt) {
  int gid = blockIdx.x * 512 + threadIdx.x;
  if (gid < 3 * 16384) {
    int m = gid >> 14, idx = gid & 16383;
    const float* W = m == 0 ? W0 : (m == 1 ? W1 : W2);
    int j = idx & 7, lane = (idx >> 3) & 63, nt = (idx >> 9) & 7, kc = idx >> 12;
    int k = kc * 32 + (lane >> 4) * 8 + j;
    int n = nt * 16 + (lane & 15);
    Wf[gid] = f2bf(W[k * DIM + n]);
  }
  int z = gid - 3 * 16384;
  if (z >= 0 && z < ncnt) cnt[z] = 0;
}

// ---------------------------------------------------------------------------
// place: dst-partitioned slot-scatter. partition = blockIdx&7 (XCD heuristic).
// Each partition scans all edges (int4 reads, L3-absorbed) but writes only its
// own 1/8 dst slice -> slice stays L2-resident, slot lines fill before evict.
// ---------------------------------------------------------------------------
__global__ __launch_bounds__(256) void place_kernel(
    const int* __restrict__ src0, const int* __restrict__ dst0,
    const int* __restrict__ src1, const int* __restrict__ dst1,
    int* __restrict__ cnt0, int* __restrict__ cnt1,
    int* __restrict__ eslot0, int* __restrict__ eslot1) {
  int part = blockIdx.x & 7;
  int bpp  = gridDim.x >> 3;       // blocks per partition
  int bidx = blockIdx.x >> 3;
  const int4* s04 = (const int4*)src0;
  const int4* d04 = (const int4*)dst0;
  const int4* s14 = (const int4*)src1;
  const int4* d14 = (const int4*)dst1;

  // layer 0: dst slice [part*6250, part*6250+6250)
  int lo = part * (N_DST0 / 8), hi = lo + (N_DST0 / 8);
  for (int i = bidx * 256 + threadIdx.x; i < E0 / 4; i += bpp * 256) {
    int4 d = d04[i]; int4 s = s04[i];
    if (d.x >= lo && d.x < hi) { int p = atomicAdd(&cnt0[d.x], 1); if (p < MAXDEG) eslot0[(size_t)d.x * MAXDEG + p] = s.x; }
    if (d.y >= lo && d.y < hi) { int p = atomicAdd(&cnt0[d.y], 1); if (p < MAXDEG) eslot0[(size_t)d.y * MAXDEG + p] = s.y; }
    if (d.z >= lo && d.z < hi) { int p = atomicAdd(&cnt0[d.z], 1); if (p < MAXDEG) eslot0[(size_t)d.z * MAXDEG + p] = s.z; }
    if (d.w >= lo && d.w < hi) { int p = atomicAdd(&cnt0[d.w], 1); if (p < MAXDEG) eslot0[(size_t)d.w * MAXDEG + p] = s.w; }
  }
  // layer 1: dst slice [part*1250, part*1250+1250)
  int lo1 = part * (N_DST1 / 8), hi1 = lo1 + (N_DST1 / 8);
  for (int i = bidx * 256 + threadIdx.x; i < E1 / 4; i += bpp * 256) {
    int4 d = d14[i]; int4 s = s14[i];
    if (d.x >= lo1 && d.x < hi1) { int p = atomicAdd(&cnt1[d.x], 1); if (p < MAXDEG) eslot1[(size_t)d.x * MAXDEG + p] = s.x; }
    if (d.y >= lo1 && d.y < hi1) { int p = atomicAdd(&cnt1[d.y], 1); if (p < MAXDEG) eslot1[(size_t)d.y * MAXDEG + p] = s.y; }
    if (d.z >= lo1 && d.z < hi1) { int p = atomicAdd(&cnt1[d.z], 1); if (p < MAXDEG) eslot1[(size_t)d.z * MAXDEG + p] = s.z; }
    if (d.w >= lo1 && d.w < hi1) { int p = atomicAdd(&cnt1[d.w], 1); if (p < MAXDEG) eslot1[(size_t)d.w * MAXDEG + p] = s.w; }
  }
}

// ---------------------------------------------------------------------------
// fc_init: h = relu(feat @ W + b), feat f32, h bf16.  m97-style staging:
// 32-row (16 KB) feat tiles double-buffered via global_load_lds width=16;
// W frags resident in LDS. 4 waves = 2 strips x 2 nt-halves per tile.
// LDS = 32 (W) + 2x16 (tiles) = 64 KB -> 2 blocks/CU.
// ---------------------------------------------------------------------------
__global__ __launch_bounds__(256) void fc_init_kernel(
    const float* __restrict__ feat, const uint16_t* __restrict__ Wf,
    const float* __restrict__ bias, uint16_t* __restrict__ hout) {
  __shared__ uint16_t wl[16384];                  // 32 KB W fragments
  __shared__ __align__(16) float tile[2][4096];   // 2 x 32 rows x 128 cols f32
  {
    const uint4* g = (const uint4*)Wf;
    uint4* s = (uint4*)wl;
    for (int i = threadIdx.x; i < 2048; i += 256) s[i] = g[i];
  }
  const int tid = threadIdx.x;
  const int w = tid >> 6, lane = tid & 63;
  const int q = lane >> 4, m16 = lane & 15;
  const int sl = w >> 1, nh = w & 1;   // strip-in-tile, nt-half

  float bv[4];
#pragma unroll
  for (int j = 0; j < 4; j++) bv[j] = bias[(nh * 4 + j) * 16 + m16];

  const int ntiles = N_SRC0 / 32;   // 6250
  const int stride = gridDim.x;

  // stage tile t (contiguous 16 KB of feat) into tile[buf]: 4 issues/wave,
  // each issue = 64 lanes x 16 B to wave-uniform LDS base + lane*16.
  auto stage = [&](int t, int buf) {
    const float* gbase = feat + (size_t)t * 4096 + w * 1024 + lane * 4;
    float* lbase = &tile[buf][w * 1024];
#pragma unroll
    for (int i = 0; i < 4; i++) {
      __builtin_amdgcn_global_load_lds(
          (const __attribute__((address_space(1))) uint32_t*)(gbase + i * 256),
          (__attribute__((address_space(3))) uint32_t*)(lbase + i * 256),
          16, 0, 0);
    }
  };

  int t = blockIdx.x;
  int cur = 0;
  if (t < ntiles) stage(t, 0);
  __syncthreads();

  while (t < ntiles) {
    int tn = t + stride;
    if (tn < ntiles) stage(tn, cur ^ 1);   // async prefetch into other buffer

    f32x4 acc[4];
#pragma unroll
    for (int j = 0; j < 4; j++) acc[j] = (f32x4){0.f, 0.f, 0.f, 0.f};

    const float* arow = &tile[cur][(sl * 16 + m16) * 128];
#pragma unroll
    for (int kc = 0; kc < 4; kc++) {
      float4 x0 = *(const float4*)(arow + kc * 32 + q * 8);
      float4 x1 = *(const float4*)(arow + kc * 32 + q * 8 + 4);
      float xs[8] = {x0.x, x0.y, x0.z, x0.w, x1.x, x1.y, x1.z, x1.w};
      bf16x8 a;
#pragma unroll
      for (int j = 0; j < 8; j++) a[j] = (short)f2bf(xs[j]);
#pragma unroll
      for (int j = 0; j < 4; j++) {
        int nt = nh * 4 + j;
        bf16x8 wv = *(const bf16x8*)&wl[((kc * 8 + nt) * 64 + lane) * 8];
        acc[j] = __builtin_amdgcn_mfma_f32_16x16x32_bf16(a, wv, acc[j], 0, 0, 0);
      }
    }

    int rowb = t * 32 + sl * 16 + q * 4;
#pragma unroll
    for (int j = 0; j < 4; j++)
#pragma unroll
      for (int r = 0; r < 4; r++) {
        float v = fmaxf(acc[j][r] + bv[j], 0.f);
        hout[(size_t)(rowb + r) * DIM + (nh * 4 + j) * 16 + m16] = f2bf(v);
      }

    __syncthreads();   // tile[cur] consumed; staged tile ready (vmcnt drain)
    cur ^= 1;
    t = tn;
  }
}

// ---------------------------------------------------------------------------
// aggregate: wave per dst, lane owns 2 feature cols; mean written as bf16.
// ---------------------------------------------------------------------------
__global__ __launch_bounds__(256) void agg_kernel(
    const int* __restrict__ eslot, const int* __restrict__ deg,
    const uint16_t* __restrict__ hsrc, uint16_t* __restrict__ hout, int n_dst) {
  int d = (blockIdx.x * 256 + threadIdx.x) >> 6;
  int lane = threadIdx.x & 63;
  if (d >= n_dst) return;
  const int* sl = eslot + (size_t)d * MAXDEG;
  int dg = deg[d];
  int dgc = dg < MAXDEG ? dg : MAXDEG;
  float a0 = 0.f, a1 = 0.f;
  int e = 0;
  for (; e + 4 <= dgc; e += 4) {
    int s0 = sl[e], s1 = sl[e + 1], s2 = sl[e + 2], s3 = sl[e + 3];
    uint32_t p0 = *(const uint32_t*)(hsrc + (size_t)s0 * DIM + lane * 2);
    uint32_t p1 = *(const uint32_t*)(hsrc + (size_t)s1 * DIM + lane * 2);
    uint32_t p2 = *(const uint32_t*)(hsrc + (size_t)s2 * DIM + lane * 2);
    uint32_t p3 = *(const uint32_t*)(hsrc + (size_t)s3 * DIM + lane * 2);
    a0 += bf2f((uint16_t)p0) + bf2f((uint16_t)p1) + bf2f((uint16_t)p2) + bf2f((uint16_t)p3);
    a1 += bf2f((uint16_t)(p0 >> 16)) + bf2f((uint16_t)(p1 >> 16)) +
          bf2f((uint16_t)(p2 >> 16)) + bf2f((uint16_t)(p3 >> 16));
  }
  for (; e < dgc; e++) {
    uint32_t p = *(const uint32_t*)(hsrc + (size_t)sl[e] * DIM + lane * 2);
    a0 += bf2f((uint16_t)p);
    a1 += bf2f((uint16_t)(p >> 16));
  }
  float inv = 1.f / fmaxf((float)dg, 1.f);
  uint32_t o = (uint32_t)f2bf(a0 * inv) | ((uint32_t)f2bf(a1 * inv) << 16);
  *(uint32_t*)(hout + (size_t)d * DIM + lane * 2) = o;
}

// ---------------------------------------------------------------------------
// sage: out = act(hself@Wself + hneigh@Wneigh + bself + bneigh)
// Both W planes in LDS (64 KB). Burst A-loads + next-strip register prefetch.
// ---------------------------------------------------------------------------
template <bool ACT, bool OUT_BF16>
__global__ __launch_bounds__(256) void sage_kernel(
    const uint16_t* __restrict__ hself, const uint16_t* __restrict__ hneigh,
    const uint16_t* __restrict__ WfS, const uint16_t* __restrict__ WfN,
    const float* __restrict__ bS, const float* __restrict__ bN,
    void* __restrict__ outp, int n_dst) {
  __shared__ uint16_t wS[16384];
  __shared__ uint16_t wN[16384];
  {
    const uint4* gS = (const uint4*)WfS;
    const uint4* gN = (const uint4*)WfN;
    uint4* sS = (uint4*)wS;
    uint4* sN = (uint4*)wN;
    for (int i = threadIdx.x; i < 2048; i += 256) { sS[i] = gS[i]; sN[i] = gN[i]; }
  }
  __syncthreads();

  int wave = (blockIdx.x * 256 + threadIdx.x) >> 6;
  int nwaves = (gridDim.x * 256) >> 6;
  int lane = threadIdx.x & 63;
  int q = lane >> 4, m16 = lane & 15;

  float bv[8];
#pragma unroll
  for (int nt = 0; nt < 8; nt++)
    bv[nt] = bS[nt * 16 + m16] + bN[nt * 16 + m16];

  const int nstrips = n_dst / 16;
  int s = wave;
  bf16x8 XS[4], XN[4];
  if (s < nstrips) {
    size_t ro = (size_t)(s * 16 + m16) * DIM + q * 8;
#pragma unroll
    for (int kc = 0; kc < 4; kc++) {
      XS[kc] = *(const bf16x8*)(hself + ro + kc * 32);
      XN[kc] = *(const bf16x8*)(hneigh + ro + kc * 32);
    }
  }

  while (s < nstrips) {
    int sn = s + nwaves;
    bf16x8 YS[4], YN[4];
    if (sn < nstrips) {
      size_t ro = (size_t)(sn * 16 + m16) * DIM + q * 8;
#pragma unroll
      for (int kc = 0; kc < 4; kc++) {
        YS[kc] = *(const bf16x8*)(hself + ro + kc * 32);
        YN[kc] = *(const bf16x8*)(hneigh + ro + kc * 32);
      }
    }

    f32x4 acc[8];
#pragma unroll
    for (int nt = 0; nt < 8; nt++) acc[nt] = (f32x4){0.f, 0.f, 0.f, 0.f};

#pragma unroll
    for (int kc = 0; kc < 4; kc++) {
#pragma unroll
      for (int nt = 0; nt < 8; nt++) {
        size_t fo = (size_t)((kc * 8 + nt) * 64 + lane) * 8;
        bf16x8 ws = *(const bf16x8*)&wS[fo];
        bf16x8 wn = *(const bf16x8*)&wN[fo];
        acc[nt] = __builtin_amdgcn_mfma_f32_16x16x32_bf16(XS[kc], ws, acc[nt], 0, 0, 0);
        acc[nt] = __builtin_amdgcn_mfma_f32_16x16x32_bf16(XN[kc], wn, acc[nt], 0, 0, 0);
      }
    }

    int m0 = s * 16;
#pragma unroll
    for (int nt = 0; nt < 8; nt++)
#pragma unroll
      for (int r = 0; r < 4; r++) {
        float v = acc[nt][r] + bv[nt];
        if (ACT) v = fmaxf(v, 0.f);
        size_t o = (size_t)(m0 + q * 4 + r) * DIM + nt * 16 + m16;
        if (OUT_BF16) ((uint16_t*)outp)[o] = f2bf(v);
        else          ((float*)outp)[o] = v;
      }

#pragma unroll
    for (int i = 0; i < 4; i++) { XS[i] = YS[i]; XN[i] = YN[i]; }
    s = sn;
  }
}

// ---------------------------------------------------------------------------
// Workspace layout (bytes), total 92,498,304 (ws_size ~409.6 MB):
//   h      @ 0           200000*128 bf16 = 51,200,000
//   h1     @ 51,200,000   50000*128 bf16 = 12,800,000
//   hn     @ 64,000,000   50000*128 bf16 = 12,800,000
//   cnt0   @ 76,800,000   50000 int      =    200,000
//   cnt1   @ 77,000,000   10000 int      =     40,000
//   eslot0 @ 77,040,000   50000*64 int   = 12,800,000
//   eslot1 @ 89,840,000   10000*64 int   =  2,560,000
//   Wf     @ 92,400,000   3*16384 bf16   =     98,304
// ---------------------------------------------------------------------------
extern "C" void kernel_launch(void* const* d_in, const int* in_sizes, int n_in,
                              void* d_out, int out_size, void* d_ws, size_t ws_size,
                              hipStream_t stream) {
  const float* feat   = (const float*)d_in[0];
  const int* src0     = (const int*)d_in[1];
  const int* dst0     = (const int*)d_in[2];
  const int* src1     = (const int*)d_in[3];
  const int* dst1     = (const int*)d_in[4];
  const float* W_init = (const float*)d_in[5];
  const float* b_init = (const float*)d_in[6];
  const float* W_self = (const float*)d_in[7];
  const float* b_self = (const float*)d_in[8];
  const float* W_neigh= (const float*)d_in[9];
  const float* b_neigh= (const float*)d_in[10];

  char* ws = (char*)d_ws;
  uint16_t* h     = (uint16_t*)(ws + 0);
  uint16_t* h1    = (uint16_t*)(ws + 51200000);
  uint16_t* hn    = (uint16_t*)(ws + 64000000);
  int*      cnt0  = (int*)(ws + 76800000);
  int*      cnt1  = (int*)(ws + 77000000);
  int*      eslot0= (int*)(ws + 77040000);
  int*      eslot1= (int*)(ws + 89840000);
  uint16_t* WfI   = (uint16_t*)(ws + 92400000);
  uint16_t* WfS   = WfI + 16384;
  uint16_t* WfN   = WfS + 16384;

  // prep W fragments + zero cnt0/cnt1 (contiguous 60000 ints)
  prep_w_kernel<<<214, 512, 0, stream>>>(W_init, W_self, W_neigh, WfI, cnt0, 60000);
  // dst-partitioned edge scatter, both layers
  place_kernel<<<1024, 256, 0, stream>>>(src0, dst0, src1, dst1,
                                         cnt0, cnt1, eslot0, eslot1);

  // h = relu(feat @ W_init + b_init)
  fc_init_kernel<<<512, 256, 0, stream>>>(feat, WfI, b_init, h);

  // ---- layer 0 ----
  agg_kernel<<<N_DST0 / 4, 256, 0, stream>>>(eslot0, cnt0, h, hn, N_DST0);
  sage_kernel<true, true><<<512, 256, 0, stream>>>(h, hn, WfS, WfN, b_self, b_neigh,
                                                   h1, N_DST0);

  // ---- layer 1 ----
  agg_kernel<<<N_DST1 / 4, 256, 0, stream>>>(eslot1, cnt1, h1, hn, N_DST1);
  sage_kernel<false, false><<<160, 256, 0, stream>>>(h1, hn, WfS, WfN, b_self, b_neigh,
                                                     d_out, N_DST1);
}